// Round 1
// baseline (142.573 us; speedup 1.0000x reference)
//
#include <hip/hip_runtime.h>
#include <math.h>

#define B_DIM 16
#define C_DIM 256
#define NV    40962
#define K_NEI 7

// Kernel 1: channel-wise mean+max reduction.
// x layout: [B][C][NV] fp32. Each thread owns one float2 (2 consecutive n) of one b.
// Row base offset = (b*C + c)*NV floats; NV is even -> 8B aligned, NOT 16B (NV%4==2),
// so float2 is the widest uniformly-aligned vector load.
__global__ void pool_kernel(const float* __restrict__ x, float4* __restrict__ pool) {
    const int NPAIR = NV / 2;                 // 20481
    int t = blockIdx.x * blockDim.x + threadIdx.x;
    if (t >= B_DIM * NPAIR) return;
    int b  = t / NPAIR;
    int n2 = t - b * NPAIR;                   // pair index within row

    const float* xb = x + (size_t)b * C_DIM * NV + 2 * (size_t)n2;

    float sx = 0.f, sy = 0.f;
    float mx = -INFINITY, my = -INFINITY;
    #pragma unroll 8
    for (int c = 0; c < C_DIM; ++c) {
        float2 v = *reinterpret_cast<const float2*>(xb + (size_t)c * NV);
        sx += v.x; sy += v.y;
        mx = fmaxf(mx, v.x);
        my = fmaxf(my, v.y);
    }
    const float inv = 1.0f / (float)C_DIM;
    // pool stored as [B][NV] of float2(avg,max); two consecutive pairs = one float4.
    // Index (b*NV + 2*n2) is even -> float4 (16B) aligned.
    float4 o;
    o.x = sx * inv; o.y = mx;                 // n = 2*n2
    o.z = sy * inv; o.w = my;                 // n = 2*n2+1
    pool[((size_t)b * NV + 2 * (size_t)n2) >> 1] = o;
}

// Kernel 2: gather 7 neighbors' (avg,max), dot with W[14], + bias, sigmoid.
__global__ void att_kernel(const float2* __restrict__ pool,
                           const int* __restrict__ idx,
                           const float* __restrict__ W,
                           const float* __restrict__ bias,
                           float* __restrict__ out) {
    int t = blockIdx.x * blockDim.x + threadIdx.x;
    if (t >= B_DIM * NV) return;
    int b = t / NV;
    int n = t - b * NV;

    const float2* pb = pool + (size_t)b * NV;
    float acc = bias[0];
    #pragma unroll
    for (int k = 0; k < K_NEI; ++k) {
        int j = idx[n * K_NEI + k];
        float2 am = pb[j];
        acc = fmaf(W[2 * k], am.x, acc);
        acc = fmaf(W[2 * k + 1], am.y, acc);
    }
    out[t] = 1.0f / (1.0f + expf(-acc));      // output layout (B,1,NV) == flat b*NV+n
}

extern "C" void kernel_launch(void* const* d_in, const int* in_sizes, int n_in,
                              void* d_out, int out_size, void* d_ws, size_t ws_size,
                              hipStream_t stream) {
    const float* x     = (const float*)d_in[0];
    const int*   neigh = (const int*)  d_in[1];
    const float* W     = (const float*)d_in[2];
    const float* bias  = (const float*)d_in[3];
    float*       out   = (float*)d_out;

    // workspace: B*NV float2 = 5.24 MB
    float4* pool4 = (float4*)d_ws;

    const int NPAIR = NV / 2;
    int t1 = B_DIM * NPAIR;
    pool_kernel<<<(t1 + 255) / 256, 256, 0, stream>>>(x, pool4);

    int t2 = B_DIM * NV;
    att_kernel<<<(t2 + 255) / 256, 256, 0, stream>>>((const float2*)d_ws, neigh, W, bias, out);
}

// Round 2
// 136.197 us; speedup vs baseline: 1.0468x; 1.0468x over previous
//
#include <hip/hip_runtime.h>
#include <math.h>

#define B_DIM 16
#define C_DIM 256
#define NV    40962
#define K_NEI 7
#define NPAIR (NV / 2)   // 20481

typedef float v2f __attribute__((ext_vector_type(2)));

// Kernel 1: channel-wise mean+max reduction, layout [b][n] float2(avg,max).
// Non-temporal loads: x is streamed exactly once (671 MB) — keep L2/L3 for pool.
__global__ void pool_kernel(const float* __restrict__ x, float4* __restrict__ pool) {
    int t = blockIdx.x * blockDim.x + threadIdx.x;
    if (t >= B_DIM * NPAIR) return;
    int b  = t / NPAIR;
    int n2 = t - b * NPAIR;

    const float* xb = x + (size_t)b * C_DIM * NV + 2 * (size_t)n2;

    float sx = 0.f, sy = 0.f;
    float mx = -INFINITY, my = -INFINITY;
    #pragma unroll 16
    for (int c = 0; c < C_DIM; ++c) {
        v2f v = __builtin_nontemporal_load(
                    reinterpret_cast<const v2f*>(xb + (size_t)c * NV));
        sx += v.x; sy += v.y;
        mx = fmaxf(mx, v.x);
        my = fmaxf(my, v.y);
    }
    const float inv = 1.0f / (float)C_DIM;
    float4 o;
    o.x = sx * inv; o.y = mx;
    o.z = sy * inv; o.w = my;
    pool[((size_t)b * NV + 2 * (size_t)n2) >> 1] = o;
}

// Kernel 2: transpose pool [b][n] -> poolT [n][b]; one vertex's 16 b-entries
// become one contiguous 128B line. LDS tile 64n x 16b with +1 pad.
__global__ void transpose_kernel(const float2* __restrict__ pool,
                                 float2* __restrict__ poolT) {
    __shared__ float2 tile[64][17];
    int n0 = blockIdx.x * 64;
    int i  = threadIdx.x & 63;
    int bq = threadIdx.x >> 6;        // 0..3
    #pragma unroll
    for (int p = 0; p < 4; ++p) {
        int b = p * 4 + bq;
        if (n0 + i < NV)
            tile[i][b] = pool[(size_t)b * NV + n0 + i];
    }
    __syncthreads();
    int valid = NV - n0; if (valid > 64) valid = 64;
    int nf4 = valid * 8;              // float4 elements to store
    float4* dst = reinterpret_cast<float4*>(poolT + (size_t)n0 * 16);
    for (int e = threadIdx.x; e < nf4; e += 256) {
        int e2 = e * 2;               // float2 element index (even)
        int n  = e2 >> 4;
        int b  = e2 & 15;             // even -> b+1 valid
        float2 a0 = tile[n][b];
        float2 a1 = tile[n][b + 1];
        dst[e] = make_float4(a0.x, a0.y, a1.x, a1.y);
    }
}

// Kernel 3 (v2): one thread per vertex n, all 16 b. Gathers are full 128B
// lines (8x float4), idx read once per n, stores wave-coalesced per b.
__global__ void att2_kernel(const float2* __restrict__ poolT,
                            const int* __restrict__ idx,
                            const float* __restrict__ W,
                            const float* __restrict__ bias,
                            float* __restrict__ out) {
    int n = blockIdx.x * 64 + threadIdx.x;
    if (n >= NV) return;

    float w[2 * K_NEI];
    #pragma unroll
    for (int i = 0; i < 2 * K_NEI; ++i) w[i] = W[i];
    float bb = bias[0];

    float acc[16];
    #pragma unroll
    for (int b = 0; b < 16; ++b) acc[b] = bb;

    #pragma unroll
    for (int k = 0; k < K_NEI; ++k) {
        int j = idx[n * K_NEI + k];
        const float4* L = reinterpret_cast<const float4*>(poolT + (size_t)j * 16);
        #pragma unroll
        for (int q = 0; q < 8; ++q) {
            float4 v = L[q];
            // identical order to v1: acc = fma(w1,max, fma(w0,avg, acc))
            acc[2 * q]     = fmaf(w[2 * k + 1], v.y, fmaf(w[2 * k], v.x, acc[2 * q]));
            acc[2 * q + 1] = fmaf(w[2 * k + 1], v.w, fmaf(w[2 * k], v.z, acc[2 * q + 1]));
        }
    }
    #pragma unroll
    for (int b = 0; b < 16; ++b)
        out[(size_t)b * NV + n] = 1.0f / (1.0f + expf(-acc[b]));
}

// Fallback (proven v1): one thread per (b,n), scattered 8B gathers.
__global__ void att_kernel(const float2* __restrict__ pool,
                           const int* __restrict__ idx,
                           const float* __restrict__ W,
                           const float* __restrict__ bias,
                           float* __restrict__ out) {
    int t = blockIdx.x * blockDim.x + threadIdx.x;
    if (t >= B_DIM * NV) return;
    int b = t / NV;
    int n = t - b * NV;

    const float2* pb = pool + (size_t)b * NV;
    float acc = bias[0];
    #pragma unroll
    for (int k = 0; k < K_NEI; ++k) {
        int j = idx[n * K_NEI + k];
        float2 am = pb[j];
        acc = fmaf(W[2 * k], am.x, acc);
        acc = fmaf(W[2 * k + 1], am.y, acc);
    }
    out[t] = 1.0f / (1.0f + expf(-acc));
}

extern "C" void kernel_launch(void* const* d_in, const int* in_sizes, int n_in,
                              void* d_out, int out_size, void* d_ws, size_t ws_size,
                              hipStream_t stream) {
    const float* x     = (const float*)d_in[0];
    const int*   neigh = (const int*)  d_in[1];
    const float* W     = (const float*)d_in[2];
    const float* bias  = (const float*)d_in[3];
    float*       out   = (float*)d_out;

    const size_t POOL_BYTES = (size_t)B_DIM * NV * sizeof(float2); // 5.24 MB

    float4* pool4 = (float4*)d_ws;
    int t1 = B_DIM * NPAIR;
    pool_kernel<<<(t1 + 255) / 256, 256, 0, stream>>>(x, pool4);

    if (ws_size >= 2 * POOL_BYTES) {
        float2* poolT = (float2*)((char*)d_ws + POOL_BYTES);
        int ntile = (NV + 63) / 64;   // 641
        transpose_kernel<<<ntile, 256, 0, stream>>>((const float2*)d_ws, poolT);
        att2_kernel<<<ntile, 64, 0, stream>>>(poolT, neigh, W, bias, out);
    } else {
        int t2 = B_DIM * NV;
        att_kernel<<<(t2 + 255) / 256, 256, 0, stream>>>((const float2*)d_ws,
                                                         neigh, W, bias, out);
    }
}